// Round 1
// baseline (509.531 us; speedup 1.0000x reference)
//
#include <hip/hip_runtime.h>
#include <cmath>

#define N_NODES_C 50000
#define N_EDGES_C 800000
#define N_FEAT_C 128
#define N_HID_C 64
#define HEADS_C 4
#define HEAD_DIM_C 16
#define N_CLASS_C 10
#define NUM_GRAPHS_C 64

static __device__ __forceinline__ float leaky(float x) { return x > 0.f ? x : 0.2f * x; }

// ---------------- CSR build ----------------
__global__ void zero_kernel(int* counts, int* cursor, float* sums, float* cnts, int n, int gsz) {
    int i = blockIdx.x * blockDim.x + threadIdx.x;
    if (i < n) { counts[i] = 0; cursor[i] = 0; }
    if (i < gsz) sums[i] = 0.f;
    if (i < NUM_GRAPHS_C) cnts[i] = 0.f;
}

__global__ void count_kernel(const int* __restrict__ dst, int* __restrict__ counts, int E) {
    int e = blockIdx.x * blockDim.x + threadIdx.x;
    if (e < E) atomicAdd(&counts[dst[e]], 1);
}

__global__ void scan_kernel(const int* __restrict__ counts, int* __restrict__ indptr, int n) {
    __shared__ int sdata[1024];
    __shared__ int carry_s;
    int t = threadIdx.x;
    if (t == 0) { carry_s = 0; indptr[0] = 0; }
    __syncthreads();
    for (int base = 0; base < n; base += 1024) {
        int i = base + t;
        int v = (i < n) ? counts[i] : 0;
        sdata[t] = v;
        __syncthreads();
        for (int off = 1; off < 1024; off <<= 1) {
            int tmp = (t >= off) ? sdata[t - off] : 0;
            __syncthreads();
            sdata[t] += tmp;
            __syncthreads();
        }
        if (i < n) indptr[i + 1] = carry_s + sdata[t];
        __syncthreads();
        if (t == 0) carry_s += sdata[1023];
        __syncthreads();
    }
}

__global__ void scatter_kernel(const int* __restrict__ src, const int* __restrict__ dst,
                               const int* __restrict__ indptr, int* __restrict__ cursor,
                               int* __restrict__ csr_src, int E) {
    int e = blockIdx.x * blockDim.x + threadIdx.x;
    if (e < E) {
        int d = dst[e];
        int pos = indptr[d] + atomicAdd(&cursor[d], 1);
        csr_src[pos] = src[e];
    }
}

// ---------------- fused GEMM + attention logits ----------------
// One wave per node (lane = output column). W staged in LDS.
template <int K, int NPB>
__global__ __launch_bounds__(256) void gemm_alpha_kernel(
    const float* __restrict__ X, const float* __restrict__ W,
    const float* __restrict__ a_src, const float* __restrict__ a_dst,
    float* __restrict__ H, float* __restrict__ As, float* __restrict__ Ad, int n)
{
    __shared__ float Wl[K * 64];
    for (int i = threadIdx.x; i < K * 64; i += 256) Wl[i] = W[i];
    __syncthreads();
    int wave = threadIdx.x >> 6, lane = threadIdx.x & 63;
    int head = lane >> 4, c = lane & 15;
    float asv = a_src[head * HEAD_DIM_C + c];
    float adv = a_dst[head * HEAD_DIM_C + c];
    for (int i = 0; i < NPB / 4; i++) {
        int node = blockIdx.x * NPB + i * 4 + wave;
        if (node >= n) continue;
        const float4* x4 = (const float4*)(X + (size_t)node * K);
        float acc = 0.f;
#pragma unroll
        for (int k4 = 0; k4 < K / 4; k4++) {
            float4 xv = x4[k4];
            acc += xv.x * Wl[(4 * k4 + 0) * 64 + lane];
            acc += xv.y * Wl[(4 * k4 + 1) * 64 + lane];
            acc += xv.z * Wl[(4 * k4 + 2) * 64 + lane];
            acc += xv.w * Wl[(4 * k4 + 3) * 64 + lane];
        }
        H[(size_t)node * 64 + lane] = acc;
        float vs = acc * asv;
        float vd = acc * adv;
        for (int off = 8; off; off >>= 1) {
            vs += __shfl_xor(vs, off, 64);
            vd += __shfl_xor(vd, off, 64);
        }
        if (c == 0) {
            As[node * 4 + head] = vs;
            Ad[node * 4 + head] = vd;
        }
    }
}

// ---------------- fused segment-softmax + aggregation ----------------
// One wave per dst node; lane = output column; head = lane/16.
__global__ __launch_bounds__(256) void gat_aggregate(
    const float* __restrict__ H, const float* __restrict__ As, const float* __restrict__ Ad,
    const int* __restrict__ indptr, const int* __restrict__ csr_src,
    const float* __restrict__ bias, float* __restrict__ Out, int n)
{
    int wave = threadIdx.x >> 6, lane = threadIdx.x & 63;
    int node = blockIdx.x * 4 + wave;
    if (node >= n) return;
    int p0 = indptr[node], p1 = indptr[node + 1];
    int deg = p1 - p0;
    int head = lane >> 4;
    float adv = Ad[node * 4 + head];

    // pass 1: per-head max of leaky(logit)
    float m = -INFINITY;
    for (int base = 0; base < deg; base += 64) {
        int s = (base + lane < deg) ? csr_src[p0 + base + lane] : 0;
        int cnt = min(64, deg - base);
        for (int j = 0; j < cnt; j++) {
            int sj = __shfl(s, j, 64);
            float lg = leaky(As[sj * 4 + head] + adv);
            m = fmaxf(m, lg);
        }
    }
    // pass 2: accumulate e and e*h[src]
    float acc = 0.f, denom = 0.f;
    for (int base = 0; base < deg; base += 64) {
        int s = (base + lane < deg) ? csr_src[p0 + base + lane] : 0;
        int cnt = min(64, deg - base);
        for (int j = 0; j < cnt; j++) {
            int sj = __shfl(s, j, 64);
            float lg = leaky(As[sj * 4 + head] + adv);
            float e = expf(lg - m);
            denom += e;
            acc += e * H[(size_t)sj * 64 + lane];
        }
    }
    float val = (deg > 0) ? acc / (denom + 1e-16f) : 0.f;
    val += bias[lane];
    Out[(size_t)node * 64 + lane] = fmaxf(val, 0.f);
}

// ---------------- pooling ----------------
__global__ void pool_kernel(const float* __restrict__ X, const int* __restrict__ batch,
                            float* __restrict__ sums, float* __restrict__ cnts, int n)
{
    int gw = (blockIdx.x * blockDim.x + threadIdx.x) >> 6;
    int lane = threadIdx.x & 63;
    int base = gw * 16;
    if (base >= n) return;
    int end = min(base + 16, n);
    int curg = batch[base];
    float acc = 0.f;
    int cnt = 0;
    for (int i = base; i < end; i++) {
        int g = batch[i];
        if (g != curg) {
            atomicAdd(&sums[curg * 64 + lane], acc);
            if (lane == 0) atomicAdd(&cnts[curg], (float)cnt);
            acc = 0.f; cnt = 0; curg = g;
        }
        acc += X[(size_t)i * 64 + lane];
        cnt++;
    }
    atomicAdd(&sums[curg * 64 + lane], acc);
    if (lane == 0) atomicAdd(&cnts[curg], (float)cnt);
}

// ---------------- final FC ----------------
__global__ void fc_kernel(const float* __restrict__ sums, const float* __restrict__ cnts,
                          const float* __restrict__ fcW, const float* __restrict__ fcb,
                          float* __restrict__ out)
{
    int idx = threadIdx.x;
    if (idx >= NUM_GRAPHS_C * N_CLASS_C) return;
    int g = idx / N_CLASS_C, c = idx % N_CLASS_C;
    float cnt = fmaxf(cnts[g], 1.f);
    float acc = fcb[c];
    for (int k = 0; k < 64; k++)
        acc += (sums[g * 64 + k] / cnt) * fcW[k * N_CLASS_C + c];
    out[g * N_CLASS_C + c] = acc;
}

extern "C" void kernel_launch(void* const* d_in, const int* in_sizes, int n_in,
                              void* d_out, int out_size, void* d_ws, size_t ws_size,
                              hipStream_t stream) {
    const float* feat = (const float*)d_in[0];
    const float* W1   = (const float*)d_in[1];
    const float* a1s  = (const float*)d_in[2];
    const float* a1d  = (const float*)d_in[3];
    const float* b1   = (const float*)d_in[4];
    const float* W2   = (const float*)d_in[5];
    const float* a2s  = (const float*)d_in[6];
    const float* a2d  = (const float*)d_in[7];
    const float* b2   = (const float*)d_in[8];
    const float* fcW  = (const float*)d_in[9];
    const float* fcb  = (const float*)d_in[10];
    const int* eidx   = (const int*)d_in[11];
    const int* batch  = (const int*)d_in[12];

    const int N = N_NODES_C;
    const int E = N_EDGES_C;
    const int* src = eidx;
    const int* dst = eidx + E;

    char* ws = (char*)d_ws;
    size_t off = 0;
    auto alloc = [&](size_t bytes) -> void* {
        void* p = ws + off;
        off += (bytes + 255) & ~(size_t)255;
        return p;
    };
    float* h       = (float*)alloc((size_t)N * 64 * 4);
    float* outb    = (float*)alloc((size_t)N * 64 * 4);
    float* As      = (float*)alloc((size_t)N * 4 * 4);
    float* Ad      = (float*)alloc((size_t)N * 4 * 4);
    int*   indptr  = (int*)alloc((size_t)(N + 1) * 4);
    int*   counts  = (int*)alloc((size_t)N * 4);
    int*   cursor  = (int*)alloc((size_t)N * 4);
    int*   csr_src = (int*)alloc((size_t)E * 4);
    float* sums    = (float*)alloc((size_t)NUM_GRAPHS_C * 64 * 4);
    float* cnts    = (float*)alloc((size_t)NUM_GRAPHS_C * 4);

    // CSR build (graph identical for both layers)
    zero_kernel<<<(N + 255) / 256, 256, 0, stream>>>(counts, cursor, sums, cnts, N, NUM_GRAPHS_C * 64);
    count_kernel<<<(E + 255) / 256, 256, 0, stream>>>(dst, counts, E);
    scan_kernel<<<1, 1024, 0, stream>>>(counts, indptr, N);
    scatter_kernel<<<(E + 255) / 256, 256, 0, stream>>>(src, dst, indptr, cursor, csr_src, E);

    // layer 1
    gemm_alpha_kernel<N_FEAT_C, 32><<<(N + 31) / 32, 256, 0, stream>>>(feat, W1, a1s, a1d, h, As, Ad, N);
    gat_aggregate<<<(N + 3) / 4, 256, 0, stream>>>(h, As, Ad, indptr, csr_src, b1, outb, N);
    // layer 2
    gemm_alpha_kernel<N_HID_C, 32><<<(N + 31) / 32, 256, 0, stream>>>(outb, W2, a2s, a2d, h, As, Ad, N);
    gat_aggregate<<<(N + 3) / 4, 256, 0, stream>>>(h, As, Ad, indptr, csr_src, b2, outb, N);

    // pool + fc
    int pool_waves = (N + 15) / 16;
    pool_kernel<<<(pool_waves * 64 + 255) / 256, 256, 0, stream>>>(outb, batch, sums, cnts, N);
    fc_kernel<<<1, 1024, 0, stream>>>(sums, cnts, fcW, fcb, (float*)d_out);
}

// Round 2
// 378.536 us; speedup vs baseline: 1.3461x; 1.3461x over previous
//
#include <hip/hip_runtime.h>
#include <cmath>

#define N_NODES_C 50000
#define N_EDGES_C 800000
#define N_FEAT_C 128
#define N_HID_C 64
#define HEADS_C 4
#define HEAD_DIM_C 16
#define N_CLASS_C 10
#define NUM_GRAPHS_C 64
#define LOG2E_C 1.44269504088896340736f

static __device__ __forceinline__ float leaky(float x) { return x > 0.f ? x : 0.2f * x; }
static __device__ __forceinline__ float sel4(float4 v, int h) {
    float ab = (h & 1) ? v.y : v.x;
    float cd = (h & 1) ? v.w : v.z;
    return (h & 2) ? cd : ab;
}

// ---------------- init ----------------
__global__ void zero_kernel(int* counts, int* cursor, float* sums, float* cnts, int n) {
    int i = blockIdx.x * blockDim.x + threadIdx.x;
    if (i < n) { counts[i] = 0; cursor[i] = 0; }
    if (i < NUM_GRAPHS_C * N_HID_C) sums[i] = 0.f;
    if (i < NUM_GRAPHS_C) cnts[i] = 0.f;
}

__global__ void count_kernel(const int* __restrict__ dst, int* __restrict__ counts, int E) {
    int e = blockIdx.x * blockDim.x + threadIdx.x;
    if (e < E) atomicAdd(&counts[dst[e]], 1);
}

// ---------------- hierarchical scan: counts -> indptr ----------------
// S1: per-block (1024 elems) sums
__global__ void scan_part(const int* __restrict__ counts, int* __restrict__ bsum, int n) {
    int b = blockIdx.x, t = threadIdx.x;  // 256 threads
    int base = b * 1024 + t * 4;
    int v = 0;
    if (base + 3 < n) {
        int4 c = *(const int4*)(counts + base);
        v = c.x + c.y + c.z + c.w;
    } else {
        for (int i = 0; i < 4; i++) if (base + i < n) v += counts[base + i];
    }
    for (int off = 32; off; off >>= 1) v += __shfl_xor(v, off, 64);
    __shared__ int ws[4];
    if ((t & 63) == 0) ws[t >> 6] = v;
    __syncthreads();
    if (t == 0) bsum[b] = ws[0] + ws[1] + ws[2] + ws[3];
}

// S2: single-wave exclusive scan of block sums (nb <= 64)
__global__ void scan_top(const int* __restrict__ bsum, int* __restrict__ boff,
                         int* __restrict__ indptr, int nb) {
    int t = threadIdx.x;
    int own = (t < nb) ? bsum[t] : 0;
    int v = own;
    for (int off = 1; off < 64; off <<= 1) {
        int u = __shfl_up(v, off, 64);
        if (t >= off) v += u;
    }
    if (t < nb) boff[t] = v - own;
    if (t == 0) indptr[0] = 0;
}

// S3: per-block scan + offset -> indptr[i+1]
__global__ void scan_block(const int* __restrict__ counts, const int* __restrict__ boff,
                           int* __restrict__ indptr, int n) {
    int b = blockIdx.x, t = threadIdx.x;  // 256 threads
    int base = b * 1024 + t * 4;
    int4 c = {0, 0, 0, 0};
    if (base + 3 < n) c = *(const int4*)(counts + base);
    else {
        if (base + 0 < n) c.x = counts[base + 0];
        if (base + 1 < n) c.y = counts[base + 1];
        if (base + 2 < n) c.z = counts[base + 2];
        if (base + 3 < n) c.w = counts[base + 3];
    }
    int s0 = c.x, s1 = s0 + c.y, s2 = s1 + c.z, s3 = s2 + c.w;
    int tsum = s3;
    int lane = t & 63, wv = t >> 6;
    int v = tsum;
    for (int off = 1; off < 64; off <<= 1) {
        int u = __shfl_up(v, off, 64);
        if (lane >= off) v += u;
    }
    __shared__ int wsum[4];
    if (lane == 63) wsum[wv] = v;
    __syncthreads();
    int woff = 0;
    for (int w = 0; w < wv; w++) woff += wsum[w];
    int excl = v - tsum + woff + boff[b];
    if (base + 0 < n) indptr[base + 1] = excl + s0;
    if (base + 1 < n) indptr[base + 2] = excl + s1;
    if (base + 2 < n) indptr[base + 3] = excl + s2;
    if (base + 3 < n) indptr[base + 4] = excl + s3;
}

__global__ void scatter_kernel(const int* __restrict__ src, const int* __restrict__ dst,
                               const int* __restrict__ indptr, int* __restrict__ cursor,
                               int* __restrict__ csr_src, int E) {
    int e = blockIdx.x * blockDim.x + threadIdx.x;
    if (e < E) {
        int d = dst[e];
        int pos = indptr[d] + atomicAdd(&cursor[d], 1);
        csr_src[pos] = src[e];
    }
}

// ---------------- fused GEMM + attention logits ----------------
// 4 waves/block, 4 nodes/wave. WT transposed in LDS, padded: [64][K+4].
template <int K>
__global__ __launch_bounds__(256) void gemm_alpha_kernel(
    const float* __restrict__ X, const float* __restrict__ W,
    const float* __restrict__ a_src, const float* __restrict__ a_dst,
    float* __restrict__ H, float* __restrict__ As, float* __restrict__ Ad, int n)
{
    __shared__ float WT[64 * (K + 4)];
    for (int i = threadIdx.x; i < K * 64; i += 256) {
        int k = i >> 6, c = i & 63;
        WT[c * (K + 4) + k] = W[i];
    }
    __syncthreads();
    int wave = threadIdx.x >> 6, lane = threadIdx.x & 63;
    int head = lane >> 4, c = lane & 15;
    int node0 = blockIdx.x * 16 + wave * 4;
    if (node0 >= n) return;
    float asv = a_src[lane];
    float adv = a_dst[lane];

    int n0 = node0, n1 = min(node0 + 1, n - 1), n2 = min(node0 + 2, n - 1), n3 = min(node0 + 3, n - 1);
    const float4* x0 = (const float4*)(X + (size_t)n0 * K);
    const float4* x1 = (const float4*)(X + (size_t)n1 * K);
    const float4* x2 = (const float4*)(X + (size_t)n2 * K);
    const float4* x3 = (const float4*)(X + (size_t)n3 * K);
    const float4* wt = (const float4*)(WT + lane * (K + 4));

    float acc0 = 0.f, acc1 = 0.f, acc2 = 0.f, acc3 = 0.f;
#pragma unroll
    for (int k4 = 0; k4 < K / 4; k4++) {
        float4 wv = wt[k4];
        float4 v0 = x0[k4], v1 = x1[k4], v2 = x2[k4], v3 = x3[k4];
        acc0 += wv.x * v0.x + wv.y * v0.y + wv.z * v0.z + wv.w * v0.w;
        acc1 += wv.x * v1.x + wv.y * v1.y + wv.z * v1.z + wv.w * v1.w;
        acc2 += wv.x * v2.x + wv.y * v2.y + wv.z * v2.z + wv.w * v2.w;
        acc3 += wv.x * v3.x + wv.y * v3.y + wv.z * v3.z + wv.w * v3.w;
    }
    float accs[4] = {acc0, acc1, acc2, acc3};
#pragma unroll
    for (int i = 0; i < 4; i++) {
        int node = node0 + i;
        if (node >= n) break;
        float a = accs[i];
        H[(size_t)node * 64 + lane] = a;
        float vs = a * asv, vd = a * adv;
#pragma unroll
        for (int off = 8; off; off >>= 1) {
            vs += __shfl_xor(vs, off, 64);
            vd += __shfl_xor(vd, off, 64);
        }
        if (c == 0) {
            As[node * 4 + head] = vs;
            Ad[node * 4 + head] = vd;
        }
    }
}

// ---------------- fused segment-softmax + aggregation ----------------
// One wave per dst node; lane = output column; head = lane>>4.
__global__ __launch_bounds__(256) void gat_aggregate(
    const float* __restrict__ H, const float* __restrict__ As, const float* __restrict__ Ad,
    const int* __restrict__ indptr, const int* __restrict__ csr_src,
    const float* __restrict__ bias, float* __restrict__ Out, int n)
{
    __shared__ float lgbuf[4][64][4];
    __shared__ int sbuf[4][64];
    int wave = threadIdx.x >> 6, lane = threadIdx.x & 63;
    int node = blockIdx.x * 4 + wave;
    if (node >= n) return;
    int p0 = indptr[node], p1 = indptr[node + 1];
    int deg = p1 - p0;
    int head = lane >> 4;
    float b = bias[lane];
    if (deg == 0) {
        Out[(size_t)node * 64 + lane] = fmaxf(b, 0.f);
        return;
    }
    float4 ad4 = ((const float4*)Ad)[node];
    bool small = (deg <= 64);

    // pass 1: lane-parallel logits + per-head max
    float4 mv = {-INFINITY, -INFINITY, -INFINITY, -INFINITY};
    for (int base = 0; base < deg; base += 64) {
        int p = p0 + base + lane;
        if (p < p1) {
            int s = csr_src[p];
            float4 as4 = ((const float4*)As)[s];
            float4 lg4;
            lg4.x = leaky(as4.x + ad4.x);
            lg4.y = leaky(as4.y + ad4.y);
            lg4.z = leaky(as4.z + ad4.z);
            lg4.w = leaky(as4.w + ad4.w);
            mv.x = fmaxf(mv.x, lg4.x);
            mv.y = fmaxf(mv.y, lg4.y);
            mv.z = fmaxf(mv.z, lg4.z);
            mv.w = fmaxf(mv.w, lg4.w);
            if (small) {
                lgbuf[wave][lane][0] = lg4.x;
                lgbuf[wave][lane][1] = lg4.y;
                lgbuf[wave][lane][2] = lg4.z;
                lgbuf[wave][lane][3] = lg4.w;
                sbuf[wave][lane] = s;
            }
        }
    }
#pragma unroll
    for (int off = 32; off; off >>= 1) {
        mv.x = fmaxf(mv.x, __shfl_xor(mv.x, off, 64));
        mv.y = fmaxf(mv.y, __shfl_xor(mv.y, off, 64));
        mv.z = fmaxf(mv.z, __shfl_xor(mv.z, off, 64));
        mv.w = fmaxf(mv.w, __shfl_xor(mv.w, off, 64));
    }
    float m = sel4(mv, head);

    float acc = 0.f, denom = 0.f;
    if (small) {
        int j = 0;
        int jend = deg & ~3;
        for (; j < jend; j += 4) {
            float lg0 = lgbuf[wave][j + 0][head];
            float lg1 = lgbuf[wave][j + 1][head];
            float lg2 = lgbuf[wave][j + 2][head];
            float lg3 = lgbuf[wave][j + 3][head];
            int s0 = sbuf[wave][j + 0];
            int s1 = sbuf[wave][j + 1];
            int s2 = sbuf[wave][j + 2];
            int s3 = sbuf[wave][j + 3];
            float e0 = exp2f((lg0 - m) * LOG2E_C);
            float e1 = exp2f((lg1 - m) * LOG2E_C);
            float e2 = exp2f((lg2 - m) * LOG2E_C);
            float e3 = exp2f((lg3 - m) * LOG2E_C);
            float h0 = H[(size_t)s0 * 64 + lane];
            float h1 = H[(size_t)s1 * 64 + lane];
            float h2 = H[(size_t)s2 * 64 + lane];
            float h3 = H[(size_t)s3 * 64 + lane];
            denom += (e0 + e1) + (e2 + e3);
            acc += e0 * h0;
            acc += e1 * h1;
            acc += e2 * h2;
            acc += e3 * h3;
        }
        for (; j < deg; j++) {
            float lg = lgbuf[wave][j][head];
            int s = sbuf[wave][j];
            float e = exp2f((lg - m) * LOG2E_C);
            denom += e;
            acc += e * H[(size_t)s * 64 + lane];
        }
    } else {
        float advh = sel4(ad4, head);
        for (int p = p0; p < p1; p++) {
            int s = csr_src[p];
            float lg = leaky(As[s * 4 + head] + advh);
            float e = exp2f((lg - m) * LOG2E_C);
            denom += e;
            acc += e * H[(size_t)s * 64 + lane];
        }
    }
    float val = acc / (denom + 1e-16f) + b;
    Out[(size_t)node * 64 + lane] = fmaxf(val, 0.f);
}

// ---------------- pooling ----------------
__global__ void pool_kernel(const float* __restrict__ X, const int* __restrict__ batch,
                            float* __restrict__ sums, float* __restrict__ cnts, int n)
{
    int gw = (blockIdx.x * blockDim.x + threadIdx.x) >> 6;
    int lane = threadIdx.x & 63;
    int base = gw * 16;
    if (base >= n) return;
    int end = min(base + 16, n);
    int curg = batch[base];
    float acc = 0.f;
    int cnt = 0;
    for (int i = base; i < end; i++) {
        int g = batch[i];
        if (g != curg) {
            atomicAdd(&sums[curg * 64 + lane], acc);
            if (lane == 0) atomicAdd(&cnts[curg], (float)cnt);
            acc = 0.f; cnt = 0; curg = g;
        }
        acc += X[(size_t)i * 64 + lane];
        cnt++;
    }
    atomicAdd(&sums[curg * 64 + lane], acc);
    if (lane == 0) atomicAdd(&cnts[curg], (float)cnt);
}

// ---------------- final FC ----------------
__global__ void fc_kernel(const float* __restrict__ sums, const float* __restrict__ cnts,
                          const float* __restrict__ fcW, const float* __restrict__ fcb,
                          float* __restrict__ out)
{
    int idx = threadIdx.x;
    if (idx >= NUM_GRAPHS_C * N_CLASS_C) return;
    int g = idx / N_CLASS_C, c = idx % N_CLASS_C;
    float cnt = fmaxf(cnts[g], 1.f);
    float acc = fcb[c];
    for (int k = 0; k < 64; k++)
        acc += (sums[g * 64 + k] / cnt) * fcW[k * N_CLASS_C + c];
    out[g * N_CLASS_C + c] = acc;
}

extern "C" void kernel_launch(void* const* d_in, const int* in_sizes, int n_in,
                              void* d_out, int out_size, void* d_ws, size_t ws_size,
                              hipStream_t stream) {
    const float* feat = (const float*)d_in[0];
    const float* W1   = (const float*)d_in[1];
    const float* a1s  = (const float*)d_in[2];
    const float* a1d  = (const float*)d_in[3];
    const float* b1   = (const float*)d_in[4];
    const float* W2   = (const float*)d_in[5];
    const float* a2s  = (const float*)d_in[6];
    const float* a2d  = (const float*)d_in[7];
    const float* b2   = (const float*)d_in[8];
    const float* fcW  = (const float*)d_in[9];
    const float* fcb  = (const float*)d_in[10];
    const int* eidx   = (const int*)d_in[11];
    const int* batch  = (const int*)d_in[12];

    const int N = N_NODES_C;
    const int E = N_EDGES_C;
    const int* src = eidx;
    const int* dst = eidx + E;

    char* ws = (char*)d_ws;
    size_t off = 0;
    auto alloc = [&](size_t bytes) -> void* {
        void* p = ws + off;
        off += (bytes + 255) & ~(size_t)255;
        return p;
    };
    float* h       = (float*)alloc((size_t)N * 64 * 4);
    float* outb    = (float*)alloc((size_t)N * 64 * 4);
    float* As      = (float*)alloc((size_t)N * 4 * 4);
    float* Ad      = (float*)alloc((size_t)N * 4 * 4);
    int*   indptr  = (int*)alloc((size_t)(N + 1) * 4);
    int*   counts  = (int*)alloc((size_t)N * 4);
    int*   cursor  = (int*)alloc((size_t)N * 4);
    int*   csr_src = (int*)alloc((size_t)E * 4);
    int*   bsum    = (int*)alloc(64 * 4);
    int*   boff    = (int*)alloc(64 * 4);
    float* sums    = (float*)alloc((size_t)NUM_GRAPHS_C * 64 * 4);
    float* cnts    = (float*)alloc((size_t)NUM_GRAPHS_C * 4);

    const int NB = (N + 1023) / 1024;  // 49

    // CSR build (graph identical for both layers)
    zero_kernel<<<(N + 255) / 256, 256, 0, stream>>>(counts, cursor, sums, cnts, N);
    count_kernel<<<(E + 255) / 256, 256, 0, stream>>>(dst, counts, E);
    scan_part<<<NB, 256, 0, stream>>>(counts, bsum, N);
    scan_top<<<1, 64, 0, stream>>>(bsum, boff, indptr, NB);
    scan_block<<<NB, 256, 0, stream>>>(counts, boff, indptr, N);
    scatter_kernel<<<(E + 255) / 256, 256, 0, stream>>>(src, dst, indptr, cursor, csr_src, E);

    // layer 1
    gemm_alpha_kernel<N_FEAT_C><<<(N + 15) / 16, 256, 0, stream>>>(feat, W1, a1s, a1d, h, As, Ad, N);
    gat_aggregate<<<(N + 3) / 4, 256, 0, stream>>>(h, As, Ad, indptr, csr_src, b1, outb, N);
    // layer 2
    gemm_alpha_kernel<N_HID_C><<<(N + 15) / 16, 256, 0, stream>>>(outb, W2, a2s, a2d, h, As, Ad, N);
    gat_aggregate<<<(N + 3) / 4, 256, 0, stream>>>(h, As, Ad, indptr, csr_src, b2, outb, N);

    // pool + fc
    int pool_waves = (N + 15) / 16;
    pool_kernel<<<(pool_waves * 64 + 255) / 256, 256, 0, stream>>>(outb, batch, sums, cnts, N);
    fc_kernel<<<1, 1024, 0, stream>>>(sums, cnts, fcW, fcb, (float*)d_out);
}

// Round 3
// 268.453 us; speedup vs baseline: 1.8980x; 1.4101x over previous
//
#include <hip/hip_runtime.h>
#include <cmath>

#define N_NODES_C 50000
#define N_EDGES_C 800000
#define N_FEAT_C 128
#define N_HID_C 64
#define HEADS_C 4
#define HEAD_DIM_C 16
#define N_CLASS_C 10
#define NUM_GRAPHS_C 64
#define LOG2E_C 1.44269504088896340736f

static __device__ __forceinline__ float leaky(float x) { return x > 0.f ? x : 0.2f * x; }
static __device__ __forceinline__ float sel4(float4 v, int h) {
    float ab = (h & 1) ? v.y : v.x;
    float cd = (h & 1) ? v.w : v.z;
    return (h & 2) ? cd : ab;
}

// ---------------- init ----------------
__global__ void zero_kernel(int* counts, int* cursor, float* sums, float* cnts, int n) {
    int i = blockIdx.x * blockDim.x + threadIdx.x;
    if (i < n) { counts[i] = 0; cursor[i] = 0; }
    if (i < NUM_GRAPHS_C * N_HID_C) sums[i] = 0.f;
    if (i < NUM_GRAPHS_C) cnts[i] = 0.f;
}

__global__ void count_kernel(const int* __restrict__ dst, int* __restrict__ counts, int E) {
    int e = blockIdx.x * blockDim.x + threadIdx.x;
    if (e < E) atomicAdd(&counts[dst[e]], 1);
}

// ---------------- hierarchical scan: counts -> indptr ----------------
__global__ void scan_part(const int* __restrict__ counts, int* __restrict__ bsum, int n) {
    int b = blockIdx.x, t = threadIdx.x;  // 256 threads
    int base = b * 1024 + t * 4;
    int v = 0;
    if (base + 3 < n) {
        int4 c = *(const int4*)(counts + base);
        v = c.x + c.y + c.z + c.w;
    } else {
        for (int i = 0; i < 4; i++) if (base + i < n) v += counts[base + i];
    }
    for (int off = 32; off; off >>= 1) v += __shfl_xor(v, off, 64);
    __shared__ int ws[4];
    if ((t & 63) == 0) ws[t >> 6] = v;
    __syncthreads();
    if (t == 0) bsum[b] = ws[0] + ws[1] + ws[2] + ws[3];
}

__global__ void scan_top(const int* __restrict__ bsum, int* __restrict__ boff,
                         int* __restrict__ indptr, int nb) {
    int t = threadIdx.x;
    int own = (t < nb) ? bsum[t] : 0;
    int v = own;
    for (int off = 1; off < 64; off <<= 1) {
        int u = __shfl_up(v, off, 64);
        if (t >= off) v += u;
    }
    if (t < nb) boff[t] = v - own;
    if (t == 0) indptr[0] = 0;
}

__global__ void scan_block(const int* __restrict__ counts, const int* __restrict__ boff,
                           int* __restrict__ indptr, int n) {
    int b = blockIdx.x, t = threadIdx.x;  // 256 threads
    int base = b * 1024 + t * 4;
    int4 c = {0, 0, 0, 0};
    if (base + 3 < n) c = *(const int4*)(counts + base);
    else {
        if (base + 0 < n) c.x = counts[base + 0];
        if (base + 1 < n) c.y = counts[base + 1];
        if (base + 2 < n) c.z = counts[base + 2];
        if (base + 3 < n) c.w = counts[base + 3];
    }
    int s0 = c.x, s1 = s0 + c.y, s2 = s1 + c.z, s3 = s2 + c.w;
    int tsum = s3;
    int lane = t & 63, wv = t >> 6;
    int v = tsum;
    for (int off = 1; off < 64; off <<= 1) {
        int u = __shfl_up(v, off, 64);
        if (lane >= off) v += u;
    }
    __shared__ int wsum[4];
    if (lane == 63) wsum[wv] = v;
    __syncthreads();
    int woff = 0;
    for (int w = 0; w < wv; w++) woff += wsum[w];
    int excl = v - tsum + woff + boff[b];
    if (base + 0 < n) indptr[base + 1] = excl + s0;
    if (base + 1 < n) indptr[base + 2] = excl + s1;
    if (base + 2 < n) indptr[base + 3] = excl + s2;
    if (base + 3 < n) indptr[base + 4] = excl + s3;
}

__global__ void scatter_kernel(const int* __restrict__ src, const int* __restrict__ dst,
                               const int* __restrict__ indptr, int* __restrict__ cursor,
                               int* __restrict__ csr_src, int E) {
    int e = blockIdx.x * blockDim.x + threadIdx.x;
    if (e < E) {
        int d = dst[e];
        int pos = indptr[d] + atomicAdd(&cursor[d], 1);
        csr_src[pos] = src[e];
    }
}

// ---------------- fused GEMM + attention logits (register-held W) ----------------
// lane = output column; lane l holds W column l in K VGPRs. X row is
// wave-uniform -> readfirstlane makes the row loads scalar (s_load).
template <int K>
__global__ __launch_bounds__(256, 2) void gemm_reg_kernel(
    const float* __restrict__ X, const float* __restrict__ W,
    const float* __restrict__ a_src, const float* __restrict__ a_dst,
    float* __restrict__ H, float* __restrict__ As, float* __restrict__ Ad,
    int n, int npw)
{
    int wid = (blockIdx.x * blockDim.x + threadIdx.x) >> 6;
    int lane = threadIdx.x & 63;
    int head = lane >> 4, c = lane & 15;
    float wreg[K];
#pragma unroll
    for (int k = 0; k < K; k++) wreg[k] = W[k * 64 + lane];
    float asv = a_src[lane], adv = a_dst[lane];
    int n0 = wid * npw;
    int n1 = min(n0 + npw, n);
    for (int node0 = n0; node0 < n1; node0++) {
        int node = __builtin_amdgcn_readfirstlane(node0);
        const float4* xr = (const float4*)(X + (size_t)node * K);
        float a0 = 0.f, a1 = 0.f, a2 = 0.f, a3 = 0.f;
#pragma unroll
        for (int k4 = 0; k4 < K / 4; k4++) {
            float4 xv = xr[k4];
            a0 += xv.x * wreg[4 * k4 + 0];
            a1 += xv.y * wreg[4 * k4 + 1];
            a2 += xv.z * wreg[4 * k4 + 2];
            a3 += xv.w * wreg[4 * k4 + 3];
        }
        float acc = (a0 + a1) + (a2 + a3);
        H[(size_t)node * 64 + lane] = acc;
        float vs = acc * asv, vd = acc * adv;
#pragma unroll
        for (int off = 8; off; off >>= 1) {
            vs += __shfl_xor(vs, off, 64);
            vd += __shfl_xor(vd, off, 64);
        }
        if (c == 0) {
            As[node * 4 + head] = vs;
            Ad[node * 4 + head] = vd;
        }
    }
}

// ---------------- fused segment-softmax + aggregation ----------------
__global__ __launch_bounds__(256) void gat_aggregate(
    const float* __restrict__ H, const float* __restrict__ As, const float* __restrict__ Ad,
    const int* __restrict__ indptr, const int* __restrict__ csr_src,
    const float* __restrict__ bias, float* __restrict__ Out, int n)
{
    __shared__ float lgbuf[4][64][4];
    __shared__ int sbuf[4][64];
    int wave = threadIdx.x >> 6, lane = threadIdx.x & 63;
    int node = blockIdx.x * 4 + wave;
    if (node >= n) return;
    int p0 = indptr[node], p1 = indptr[node + 1];
    int deg = p1 - p0;
    int head = lane >> 4;
    float b = bias[lane];
    if (deg == 0) {
        Out[(size_t)node * 64 + lane] = fmaxf(b, 0.f);
        return;
    }
    float4 ad4 = ((const float4*)Ad)[node];
    bool small = (deg <= 64);

    float4 mv = {-INFINITY, -INFINITY, -INFINITY, -INFINITY};
    for (int base = 0; base < deg; base += 64) {
        int p = p0 + base + lane;
        if (p < p1) {
            int s = csr_src[p];
            float4 as4 = ((const float4*)As)[s];
            float4 lg4;
            lg4.x = leaky(as4.x + ad4.x);
            lg4.y = leaky(as4.y + ad4.y);
            lg4.z = leaky(as4.z + ad4.z);
            lg4.w = leaky(as4.w + ad4.w);
            mv.x = fmaxf(mv.x, lg4.x);
            mv.y = fmaxf(mv.y, lg4.y);
            mv.z = fmaxf(mv.z, lg4.z);
            mv.w = fmaxf(mv.w, lg4.w);
            if (small) {
                lgbuf[wave][lane][0] = lg4.x;
                lgbuf[wave][lane][1] = lg4.y;
                lgbuf[wave][lane][2] = lg4.z;
                lgbuf[wave][lane][3] = lg4.w;
                sbuf[wave][lane] = s;
            }
        }
    }
#pragma unroll
    for (int off = 32; off; off >>= 1) {
        mv.x = fmaxf(mv.x, __shfl_xor(mv.x, off, 64));
        mv.y = fmaxf(mv.y, __shfl_xor(mv.y, off, 64));
        mv.z = fmaxf(mv.z, __shfl_xor(mv.z, off, 64));
        mv.w = fmaxf(mv.w, __shfl_xor(mv.w, off, 64));
    }
    float m = sel4(mv, head);

    float acc = 0.f, denom = 0.f;
    if (small) {
        int j = 0;
        int jend = deg & ~3;
        for (; j < jend; j += 4) {
            float lg0 = lgbuf[wave][j + 0][head];
            float lg1 = lgbuf[wave][j + 1][head];
            float lg2 = lgbuf[wave][j + 2][head];
            float lg3 = lgbuf[wave][j + 3][head];
            int s0 = sbuf[wave][j + 0];
            int s1 = sbuf[wave][j + 1];
            int s2 = sbuf[wave][j + 2];
            int s3 = sbuf[wave][j + 3];
            float e0 = exp2f((lg0 - m) * LOG2E_C);
            float e1 = exp2f((lg1 - m) * LOG2E_C);
            float e2 = exp2f((lg2 - m) * LOG2E_C);
            float e3 = exp2f((lg3 - m) * LOG2E_C);
            float h0 = H[(size_t)s0 * 64 + lane];
            float h1 = H[(size_t)s1 * 64 + lane];
            float h2 = H[(size_t)s2 * 64 + lane];
            float h3 = H[(size_t)s3 * 64 + lane];
            denom += (e0 + e1) + (e2 + e3);
            acc += e0 * h0;
            acc += e1 * h1;
            acc += e2 * h2;
            acc += e3 * h3;
        }
        for (; j < deg; j++) {
            float lg = lgbuf[wave][j][head];
            int s = sbuf[wave][j];
            float e = exp2f((lg - m) * LOG2E_C);
            denom += e;
            acc += e * H[(size_t)s * 64 + lane];
        }
    } else {
        float advh = sel4(ad4, head);
        for (int p = p0; p < p1; p++) {
            int s = csr_src[p];
            float lg = leaky(As[s * 4 + head] + advh);
            float e = exp2f((lg - m) * LOG2E_C);
            denom += e;
            acc += e * H[(size_t)s * 64 + lane];
        }
    }
    float val = acc / (denom + 1e-16f) + b;
    Out[(size_t)node * 64 + lane] = fmaxf(val, 0.f);
}

// ---------------- pooling ----------------
__global__ void pool_kernel(const float* __restrict__ X, const int* __restrict__ batch,
                            float* __restrict__ sums, float* __restrict__ cnts, int n)
{
    int gw = (blockIdx.x * blockDim.x + threadIdx.x) >> 6;
    int lane = threadIdx.x & 63;
    int base = gw * 16;
    if (base >= n) return;
    int end = min(base + 16, n);
    int curg = batch[base];
    float acc = 0.f;
    int cnt = 0;
    for (int i = base; i < end; i++) {
        int g = batch[i];
        if (g != curg) {
            atomicAdd(&sums[curg * 64 + lane], acc);
            if (lane == 0) atomicAdd(&cnts[curg], (float)cnt);
            acc = 0.f; cnt = 0; curg = g;
        }
        acc += X[(size_t)i * 64 + lane];
        cnt++;
    }
    atomicAdd(&sums[curg * 64 + lane], acc);
    if (lane == 0) atomicAdd(&cnts[curg], (float)cnt);
}

// ---------------- final FC ----------------
__global__ void fc_kernel(const float* __restrict__ sums, const float* __restrict__ cnts,
                          const float* __restrict__ fcW, const float* __restrict__ fcb,
                          float* __restrict__ out)
{
    int idx = threadIdx.x;
    if (idx >= NUM_GRAPHS_C * N_CLASS_C) return;
    int g = idx / N_CLASS_C, c = idx % N_CLASS_C;
    float cnt = fmaxf(cnts[g], 1.f);
    float acc = fcb[c];
    for (int k = 0; k < 64; k++)
        acc += (sums[g * 64 + k] / cnt) * fcW[k * N_CLASS_C + c];
    out[g * N_CLASS_C + c] = acc;
}

extern "C" void kernel_launch(void* const* d_in, const int* in_sizes, int n_in,
                              void* d_out, int out_size, void* d_ws, size_t ws_size,
                              hipStream_t stream) {
    const float* feat = (const float*)d_in[0];
    const float* W1   = (const float*)d_in[1];
    const float* a1s  = (const float*)d_in[2];
    const float* a1d  = (const float*)d_in[3];
    const float* b1   = (const float*)d_in[4];
    const float* W2   = (const float*)d_in[5];
    const float* a2s  = (const float*)d_in[6];
    const float* a2d  = (const float*)d_in[7];
    const float* b2   = (const float*)d_in[8];
    const float* fcW  = (const float*)d_in[9];
    const float* fcb  = (const float*)d_in[10];
    const int* eidx   = (const int*)d_in[11];
    const int* batch  = (const int*)d_in[12];

    const int N = N_NODES_C;
    const int E = N_EDGES_C;
    const int* src = eidx;
    const int* dst = eidx + E;

    char* ws = (char*)d_ws;
    size_t off = 0;
    auto alloc = [&](size_t bytes) -> void* {
        void* p = ws + off;
        off += (bytes + 255) & ~(size_t)255;
        return p;
    };
    float* h       = (float*)alloc((size_t)N * 64 * 4);
    float* outb    = (float*)alloc((size_t)N * 64 * 4);
    float* As      = (float*)alloc((size_t)N * 4 * 4);
    float* Ad      = (float*)alloc((size_t)N * 4 * 4);
    int*   indptr  = (int*)alloc((size_t)(N + 1) * 4);
    int*   counts  = (int*)alloc((size_t)N * 4);
    int*   cursor  = (int*)alloc((size_t)N * 4);
    int*   csr_src = (int*)alloc((size_t)E * 4);
    int*   bsum    = (int*)alloc(64 * 4);
    int*   boff    = (int*)alloc(64 * 4);
    float* sums    = (float*)alloc((size_t)NUM_GRAPHS_C * 64 * 4);
    float* cnts    = (float*)alloc((size_t)NUM_GRAPHS_C * 4);

    const int NB = (N + 1023) / 1024;  // 49

    // CSR build (graph identical for both layers)
    zero_kernel<<<(N + 255) / 256, 256, 0, stream>>>(counts, cursor, sums, cnts, N);
    count_kernel<<<(E + 255) / 256, 256, 0, stream>>>(dst, counts, E);
    scan_part<<<NB, 256, 0, stream>>>(counts, bsum, N);
    scan_top<<<1, 64, 0, stream>>>(bsum, boff, indptr, NB);
    scan_block<<<NB, 256, 0, stream>>>(counts, boff, indptr, N);
    scatter_kernel<<<(E + 255) / 256, 256, 0, stream>>>(src, dst, indptr, cursor, csr_src, E);

    // layer 1: K=128, 2048 waves (512 blocks x 4 waves)
    {
        const int WAVES = 2048;
        int npw = (N + WAVES - 1) / WAVES;
        gemm_reg_kernel<N_FEAT_C><<<WAVES / 4, 256, 0, stream>>>(feat, W1, a1s, a1d, h, As, Ad, N, npw);
    }
    gat_aggregate<<<(N + 3) / 4, 256, 0, stream>>>(h, As, Ad, indptr, csr_src, b1, outb, N);
    // layer 2: K=64, 4096 waves
    {
        const int WAVES = 4096;
        int npw = (N + WAVES - 1) / WAVES;
        gemm_reg_kernel<N_HID_C><<<WAVES / 4, 256, 0, stream>>>(outb, W2, a2s, a2d, h, As, Ad, N, npw);
    }
    gat_aggregate<<<(N + 3) / 4, 256, 0, stream>>>(h, As, Ad, indptr, csr_src, b2, outb, N);

    // pool + fc
    int pool_waves = (N + 15) / 16;
    pool_kernel<<<(pool_waves * 64 + 255) / 256, 256, 0, stream>>>(outb, batch, sums, cnts, N);
    fc_kernel<<<1, 1024, 0, stream>>>(sums, cnts, fcW, fcb, (float*)d_out);
}